// Round 9
// baseline (349.118 us; speedup 1.0000x reference)
//
#include <hip/hip_runtime.h>

#define NB 16
#define NS 512
#define ND 256
#define NH 8
#define NFB 128
#define NK 64
#define NFC 32

using f16 = _Float16;
using f16x4 = __attribute__((ext_vector_type(4))) f16;
using f16x8 = __attribute__((ext_vector_type(8))) f16;
using f32x4 = __attribute__((ext_vector_type(4))) float;

__device__ inline float waveReduceSum(float v) {
    #pragma unroll
    for (int off = 32; off; off >>= 1) v += __shfl_down(v, off);
    return v;
}

__device__ inline f32x4 mfma16(f16x8 a, f16x8 b, f32x4 c) {
    return __builtin_amdgcn_mfma_f32_16x16x32_f16(a, b, c, 0, 0, 0);
}

// ---------------------------------------------------------------- prep: mt | convert | bsum | cv in one dispatch
__global__ __launch_bounds__(256) void k_prep(const float* __restrict__ W1, const float* __restrict__ W2,
                                              f16* __restrict__ Mth,
                                              const float* __restrict__ Et_in, const float* __restrict__ Ei_in,
                                              f16* __restrict__ Ot, f16* __restrict__ Oi,
                                              const float* __restrict__ Bt_in, const float* __restrict__ Bi_in,
                                              float* __restrict__ Bt, float* __restrict__ Bi,
                                              const float* __restrict__ Ct, const float* __restrict__ Ci,
                                              float* __restrict__ Cv) {
    __shared__ float Wa[64][36];
    __shared__ float Wb[64][36];
    int bid = blockIdx.x;
    int tid = threadIdx.x;

    if (bid < 128) {
        // ---- Mt[h][j][i] = sum_e W2[h,j,e]*W1[h,i,e]
        int h  = bid >> 4;
        int j0 = ((bid >> 2) & 3) * 64;
        int i0 = (bid & 3) * 64;
        const float* A  = W2 + (size_t)h * ND * ND;
        const float* Bm = W1 + (size_t)h * ND * ND;
        int r = tid >> 4, c = tid & 15;
        float acc[4][4] = {};
        for (int d0 = 0; d0 < ND; d0 += 32) {
            __syncthreads();
            #pragma unroll
            for (int i = 0; i < 2; ++i) {
                int sid = tid + i * 256;
                int row = sid >> 3, seg = sid & 7;
                *(float4*)&Wa[row][seg * 4] = *(const float4*)&A [(size_t)(j0 + row) * ND + d0 + seg * 4];
                *(float4*)&Wb[row][seg * 4] = *(const float4*)&Bm[(size_t)(i0 + row) * ND + d0 + seg * 4];
            }
            __syncthreads();
            #pragma unroll 8
            for (int d = 0; d < 32; ++d) {
                float a0 = Wa[r*4+0][d], a1 = Wa[r*4+1][d], a2 = Wa[r*4+2][d], a3 = Wa[r*4+3][d];
                float b0 = Wb[c*4+0][d], b1 = Wb[c*4+1][d], b2 = Wb[c*4+2][d], b3 = Wb[c*4+3][d];
                acc[0][0] += a0*b0; acc[0][1] += a0*b1; acc[0][2] += a0*b2; acc[0][3] += a0*b3;
                acc[1][0] += a1*b0; acc[1][1] += a1*b1; acc[1][2] += a1*b2; acc[1][3] += a1*b3;
                acc[2][0] += a2*b0; acc[2][1] += a2*b1; acc[2][2] += a2*b2; acc[2][3] += a2*b3;
                acc[3][0] += a3*b0; acc[3][1] += a3*b1; acc[3][2] += a3*b2; acc[3][3] += a3*b3;
            }
        }
        #pragma unroll
        for (int a = 0; a < 4; ++a)
            #pragma unroll
            for (int bb = 0; bb < 4; ++bb)
                Mth[(size_t)h * ND * ND + (size_t)(j0 + r * 4 + a) * ND + (i0 + c * 4 + bb)] = (f16)acc[a][bb];
    } else if (bid < 128 + 4096) {
        // ---- convert E -> f16
        const int n4 = NB * NS * ND / 4;
        int i = (bid - 128) * 256 + tid;
        const float* src; f16* dst;
        if (i < n4) { src = Et_in; dst = Ot; }
        else        { src = Ei_in; dst = Oi; i -= n4; }
        float4 v = ((const float4*)src)[i];
        f16x4 o = { (f16)v.x, (f16)v.y, (f16)v.z, (f16)v.w };
        ((f16x4*)dst)[i] = o;
    } else if (bid < 128 + 8192) {
        // ---- Bvec = sum over FB
        int wid = ((bid - 128 - 4096) * 256 + tid) >> 6;
        int lane = tid & 63;
        const float* src; float* dst; int row;
        if (wid < NB * NS) { src = Bt_in; dst = Bt; row = wid; }
        else               { src = Bi_in; dst = Bi; row = wid - NB * NS; }
        float2 v = ((const float2*)(src + (size_t)row * NFB))[lane];
        float s = waveReduceSum(v.x + v.y);
        if (lane == 0) dst[row] = s;
    } else {
        // ---- Cv = 0.5*KLD(Ci,Cm)+0.5*KLD(Ct,Cm)
        int gw = ((bid - 128 - 8192) * 256 + tid) >> 6;
        int lane = tid & 63;
        const float* pt = Ct + ((size_t)gw * NK + lane) * NFC;
        const float* pi = Ci + ((size_t)gw * NK + lane) * NFC;
        float st = 0.f, si = 0.f;
        #pragma unroll
        for (int j = 0; j < NFC; j += 4) {
            float4 vt = *(const float4*)(pt + j); st += vt.x + vt.y + vt.z + vt.w;
            float4 vi = *(const float4*)(pi + j); si += vi.x + vi.y + vi.z + vi.w;
        }
        float cm = 0.5f * (st + si);
        float yp = fminf(fmaxf(cm, 1e-7f), 1.0f);
        float y1 = fminf(fmaxf(si, 1e-7f), 1.0f);
        float y2 = fminf(fmaxf(st, 1e-7f), 1.0f);
        float term = 0.5f * (y1 * logf(y1 / yp) + y2 * logf(y2 / yp));
        term = waveReduceSum(term);
        if (lane == 0) Cv[gw] = term;
    }
}

// ---------------------------------------------------------------- attn4 (R14)
// R13 (303.6us end-to-end, attn 114.5us) + phase-1 Ms staging REMOVED: A-frags read direct from
// global Mth (1MB, L2-resident, 128-block reuse — R12 proved caches serve these addresses; its
// regression was phase-2's 16x-repeated 8B direct loads, which stay LDS-staged here). Drops 16 of
// 32 barriers + 128KB/block of ds traffic; phase-1 jc-loads now software-pipeline under MFMAs with
// no fences. Occupancy is register-capped at 2 waves/SIMD (R13 lesson: LDS halved, occupancy
// unchanged) so the lever is serialization, not waves. launch_bounds(256,2) = the proven shape.
__global__ __launch_bounds__(256, 2) void k_attn4(const f16* __restrict__ Eft, const f16* __restrict__ Efi,
                                                  const f16* __restrict__ Mth,
                                                  const float* __restrict__ Bst, const float* __restrict__ Bsi,
                                                  float* __restrict__ PEt, float* __restrict__ PBt,
                                                  float* __restrict__ PEi, float* __restrict__ PBi) {
    int x = blockIdx.x;
    const f16* E; const float* Bvg; float *PE, *PB;
    if (x < 512) { E = Eft; Bvg = Bst; PE = PEt; PB = PBt; }
    else         { x -= 512; E = Efi; Bvg = Bsi; PE = PEi; PB = PBi; }
    int b = x >> 5, h = (x >> 2) & 7;
    int sc = x & 3;
    int s0 = sc * 128;
    const f16* Ebase = E + (size_t)b * NS * ND;
    const f16* Mh = Mth + (size_t)h * ND * ND;
    float* PEo = PE + (size_t)((b * NH + h) * 4 + sc) * NS;
    float* PBo = PB + (size_t)((b * NH + h) * 4 + sc) * NS;

    __shared__ f16 smem[2 * 32 * 264];      // two 32-row buffers (phase 2 only)
    __shared__ float pe_s[NS], pb_s[NS];

    int tid = threadIdx.x;
    int lane = tid & 63, w = tid >> 6;
    int l16 = lane & 15, ch = lane >> 4;

    pe_s[tid] = 0.f; pe_s[tid + 256] = 0.f;
    pb_s[tid] = 0.f; pb_s[tid + 256] = 0.f;

    int sw0 = s0 + w * 32;   // this wave's 32 s-rows

    // hoist E B-frags for the P-phase (standard layout): 16 x 16B = 64 VGPRs
    f16x8 ebf[2][8];
    #pragma unroll
    for (int st = 0; st < 2; ++st)
        #pragma unroll
        for (int ki = 0; ki < 8; ++ki)
            ebf[st][ki] = *(const f16x8*)&Ebase[(size_t)(sw0 + st * 16 + l16) * ND + ki * 32 + ch * 8];

    // B-weights for this lane's 8 accumulator s-rows (s = sw0 + st*16 + 4*ch + r)
    float bvr[2][4];
    #pragma unroll
    for (int st = 0; st < 2; ++st)
        #pragma unroll
        for (int r = 0; r < 4; ++r)
            bvr[st][r] = Bvg[b * NS + sw0 + st * 16 + 4 * ch + r];

    // ---- phase 1: P into af[st][jc] (A-frag form, permuted k-map slot(ch,j') -> 16*(j'>>2)+4*ch+(j'&3))
    // A-frags DIRECT from global Mh (validated numerically in R12). Barrier-free; jc+1 loads
    // pipeline under jc's 32 MFMAs.
    f16x8 af[2][8];
    #pragma unroll
    for (int jc = 0; jc < 8; ++jc) {
        f32x4 acc[2][2] = {};   // [jTile(m)][sTile(n)]
        #pragma unroll
        for (int ki = 0; ki < 8; ++ki) {
            f16x8 a0 = *(const f16x8*)&Mh[(size_t)(jc * 32 + l16)      * ND + ki * 32 + ch * 8];
            f16x8 a1 = *(const f16x8*)&Mh[(size_t)(jc * 32 + 16 + l16) * ND + ki * 32 + ch * 8];
            acc[0][0] = mfma16(a0, ebf[0][ki], acc[0][0]);
            acc[0][1] = mfma16(a0, ebf[1][ki], acc[0][1]);
            acc[1][0] = mfma16(a1, ebf[0][ki], acc[1][0]);
            acc[1][1] = mfma16(a1, ebf[1][ki], acc[1][1]);
        }
        #pragma unroll
        for (int st = 0; st < 2; ++st) {
            f16x8 v;
            #pragma unroll
            for (int r = 0; r < 4; ++r) { v[r] = (f16)acc[0][st][r]; v[4 + r] = (f16)acc[1][st][r]; }
            af[st][jc] = v;
        }
    }

    // ---- phase 2: double-buffered t-sweep, 32-row tiles, 1 barrier/iter (proven R13 path)
    int4 v[4];
    #pragma unroll
    for (int i = 0; i < 4; ++i) {
        int sid = tid + i * 256;
        int row = sid >> 5, seg = sid & 31;
        v[i] = *(const int4*)&Ebase[(size_t)row * ND + seg * 8];
    }
    #pragma unroll
    for (int i = 0; i < 4; ++i) {
        int sid = tid + i * 256;
        int row = sid >> 5, seg = sid & 31;
        *(int4*)&smem[row * 264 + seg * 8] = v[i];
    }

    for (int t = 0; t < 16; ++t) {
        f16* cur = smem + (t & 1) * (32 * 264);
        f16* nxt = smem + ((t + 1) & 1) * (32 * 264);
        if (t < 15) {
            int t0n = (t + 1) * 32;
            #pragma unroll
            for (int i = 0; i < 4; ++i) {
                int sid = tid + i * 256;
                int row = sid >> 5, seg = sid & 31;
                v[i] = *(const int4*)&Ebase[(size_t)(t0n + row) * ND + seg * 8];
            }
        }
        __syncthreads();   // cur writes visible; nxt reads (iter t-1) done; pe_s init visible at t=0
        int t0 = t * 32;
        f32x4 sacc[2][2] = {};   // [sTile(m)][tTile(n)]
        #pragma unroll
        for (int kk = 0; kk < 8; ++kk)
            #pragma unroll
            for (int nt = 0; nt < 2; ++nt) {
                const f16* ep = &cur[(nt * 16 + l16) * 264 + kk * 32 + 4 * ch];
                f16x4 lo = *(const f16x4*)ep;
                f16x4 hi = *(const f16x4*)(ep + 16);
                f16x8 bf = { lo[0], lo[1], lo[2], lo[3], hi[0], hi[1], hi[2], hi[3] };
                sacc[0][nt] = mfma16(af[0][kk], bf, sacc[0][nt]);
                sacc[1][nt] = mfma16(af[1][kk], bf, sacc[1][nt]);
            }
        if (t < 15) {
            #pragma unroll
            for (int i = 0; i < 4; ++i) {
                int sid = tid + i * 256;
                int row = sid >> 5, seg = sid & 31;
                *(int4*)&nxt[row * 264 + seg * 8] = v[i];
            }
        }
        #pragma unroll
        for (int nt = 0; nt < 2; ++nt) {
            float se = 0.f, sw = 0.f;
            #pragma unroll
            for (int st = 0; st < 2; ++st)
                #pragma unroll
                for (int r = 0; r < 4; ++r) {
                    float e = __expf(sacc[st][nt][r] * 0.0625f);
                    se += e; sw += bvr[st][r] * e;
                }
            se += __shfl_down(se, 32); se += __shfl_down(se, 16);
            sw += __shfl_down(sw, 32); sw += __shfl_down(sw, 16);
            if (ch == 0) {
                atomicAdd(&pe_s[t0 + nt * 16 + l16], se);
                atomicAdd(&pb_s[t0 + nt * 16 + l16], sw);
            }
        }
    }
    __syncthreads();
    // flush partials: plain coalesced stores to this block's private (b,h,sc) slice — no atomics
    PEo[tid]       = pe_s[tid];
    PEo[tid + 256] = pe_s[tid + 256];
    PBo[tid]       = pb_s[tid];
    PBo[tid + 256] = pb_s[tid + 256];
}

// ---------------------------------------------------------------- cos stage: reduce sc-partials, tv/iv per (b,h,s)
__global__ __launch_bounds__(512) void k_cos(const float* __restrict__ PEt, const float* __restrict__ PBt,
                                             const float* __restrict__ PEi, const float* __restrict__ PBi,
                                             float* __restrict__ TV, float* __restrict__ IV) {
    int bh = blockIdx.x;          // b*NH + h, 0..127
    int s = threadIdx.x;
    float pet = 0.f, pbt = 0.f, pei = 0.f, pbi = 0.f;
    #pragma unroll
    for (int sc = 0; sc < 4; ++sc) {
        size_t idx = (size_t)(bh * 4 + sc) * NS + s;
        pet += PEt[idx]; pbt += PBt[idx];
        pei += PEi[idx]; pbi += PBi[idx];
    }
    TV[(size_t)bh * NS + s] = pbt / pet;
    IV[(size_t)bh * NS + s] = pbi / pei;
}

// ---------------------------------------------------------------- cos + 2x layernorm + combine
__device__ inline float blockSum512(float v, float* rbuf) {
    v = waveReduceSum(v);
    int lane = threadIdx.x & 63, w = threadIdx.x >> 6;
    __syncthreads();
    if (lane == 0) rbuf[w] = v;
    __syncthreads();
    float s = 0.f;
    #pragma unroll
    for (int i = 0; i < 8; ++i) s += rbuf[i];
    return s;
}

__global__ __launch_bounds__(512) void k_final(const float* __restrict__ TV, const float* __restrict__ IV,
                                               const float* __restrict__ Cv,
                                               const float* __restrict__ gbs, const float* __restrict__ bbs,
                                               const float* __restrict__ gcs, const float* __restrict__ bcs,
                                               float* __restrict__ out) {
    __shared__ float rbuf[8];
    int b = blockIdx.x, s = threadIdx.x;
    float dot = 0.f, nt = 0.f, nu = 0.f;
    #pragma unroll
    for (int h = 0; h < NH; ++h) {
        float tv = TV[(size_t)(b * NH + h) * NS + s];
        float iv = IV[(size_t)(b * NH + h) * NS + s];
        dot += tv * iv; nt += tv * tv; nu += iv * iv;
    }
    float cosv = -(dot * rsqrtf(fmaxf(nt, 1e-12f)) * rsqrtf(fmaxf(nu, 1e-12f)));

    float mc = blockSum512(cosv, rbuf) * (1.f / 512.f);
    float dc = cosv - mc;
    float vc = blockSum512(dc * dc, rbuf) * (1.f / 512.f);
    float BS = dc * rsqrtf(vc + 1e-16f) * gbs[s] + bbs[s];

    float cv = Cv[(size_t)b * NS + s];
    float mv = blockSum512(cv, rbuf) * (1.f / 512.f);
    float dv = cv - mv;
    float vv = blockSum512(dv * dv, rbuf) * (1.f / 512.f);
    float CS = dv * rsqrtf(vv + 1e-16f) * gcs[s] + bcs[s];

    out[(size_t)b * NS + s] = BS + CS;
    out[(size_t)NB * NS + (size_t)b * NS + s] = BS;
    out[(size_t)2 * NB * NS + (size_t)b * NS + s] = CS;
}

extern "C" void kernel_launch(void* const* d_in, const int* in_sizes, int n_in,
                              void* d_out, int out_size, void* d_ws, size_t ws_size,
                              hipStream_t stream) {
    const float* B_target   = (const float*)d_in[0];
    const float* B_infected = (const float*)d_in[1];
    const float* E_target   = (const float*)d_in[2];
    const float* E_infected = (const float*)d_in[3];
    const float* C_target   = (const float*)d_in[4];
    const float* C_infected = (const float*)d_in[5];
    const float* W1  = (const float*)d_in[8];
    const float* W2  = (const float*)d_in[9];
    const float* gbs = (const float*)d_in[10];
    const float* bbs = (const float*)d_in[11];
    const float* gcs = (const float*)d_in[12];
    const float* bcs = (const float*)d_in[13];
    float* out = (float*)d_out;

    char* ws = (char*)d_ws;
    size_t off = 0;
    auto alloc = [&](size_t n) { char* p = ws + off; off = (off + n + 255) & ~(size_t)255; return p; };
    float* Bt  = (float*)alloc((size_t)NB * NS * 4);
    float* Bi  = (float*)alloc((size_t)NB * NS * 4);
    float* Cv  = (float*)alloc((size_t)NB * NS * 4);
    float* PEt = (float*)alloc((size_t)NB * NH * 4 * NS * 4);   // per-(b,h,sc) partials
    float* PBt = (float*)alloc((size_t)NB * NH * 4 * NS * 4);
    float* PEi = (float*)alloc((size_t)NB * NH * 4 * NS * 4);
    float* PBi = (float*)alloc((size_t)NB * NH * 4 * NS * 4);
    float* TV  = (float*)alloc((size_t)NB * NH * NS * 4);
    float* IV  = (float*)alloc((size_t)NB * NH * NS * 4);
    f16* Mth = (f16*)alloc((size_t)NH * ND * ND * 2);
    f16* Eft = (f16*)alloc((size_t)NB * NS * ND * 2);
    f16* Efi = (f16*)alloc((size_t)NB * NS * ND * 2);

    k_prep<<<128 + 8192 + 2048, 256, 0, stream>>>(W1, W2, Mth,
                                                  E_target, E_infected, Eft, Efi,
                                                  B_target, B_infected, Bt, Bi,
                                                  C_target, C_infected, Cv);
    k_attn4<<<1024, 256, 0, stream>>>(Eft, Efi, Mth, Bt, Bi, PEt, PBt, PEi, PBi);
    k_cos<<<NB * NH, 512, 0, stream>>>(PEt, PBt, PEi, PBi, TV, IV);
    k_final<<<NB, 512, 0, stream>>>(TV, IV, Cv, gbs, bbs, gcs, bcs, out);
}

// Round 10
// 317.766 us; speedup vs baseline: 1.0987x; 1.0987x over previous
//
#include <hip/hip_runtime.h>

#define NB 16
#define NS 512
#define ND 256
#define NH 8
#define NFB 128
#define NK 64
#define NFC 32

using f16 = _Float16;
using f16x4 = __attribute__((ext_vector_type(4))) f16;
using f16x8 = __attribute__((ext_vector_type(8))) f16;
using f32x4 = __attribute__((ext_vector_type(4))) float;

__device__ inline float waveReduceSum(float v) {
    #pragma unroll
    for (int off = 32; off; off >>= 1) v += __shfl_down(v, off);
    return v;
}

__device__ inline f32x4 mfma16(f16x8 a, f16x8 b, f32x4 c) {
    return __builtin_amdgcn_mfma_f32_16x16x32_f16(a, b, c, 0, 0, 0);
}

// ---------------------------------------------------------------- prep: mt | convert | bsum | cv in one dispatch
__global__ __launch_bounds__(256) void k_prep(const float* __restrict__ W1, const float* __restrict__ W2,
                                              f16* __restrict__ Mth,
                                              const float* __restrict__ Et_in, const float* __restrict__ Ei_in,
                                              f16* __restrict__ Ot, f16* __restrict__ Oi,
                                              const float* __restrict__ Bt_in, const float* __restrict__ Bi_in,
                                              float* __restrict__ Bt, float* __restrict__ Bi,
                                              const float* __restrict__ Ct, const float* __restrict__ Ci,
                                              float* __restrict__ Cv) {
    __shared__ float Wa[64][36];
    __shared__ float Wb[64][36];
    int bid = blockIdx.x;
    int tid = threadIdx.x;

    if (bid < 128) {
        // ---- Mt[h][j][i] = sum_e W2[h,j,e]*W1[h,i,e]
        int h  = bid >> 4;
        int j0 = ((bid >> 2) & 3) * 64;
        int i0 = (bid & 3) * 64;
        const float* A  = W2 + (size_t)h * ND * ND;
        const float* Bm = W1 + (size_t)h * ND * ND;
        int r = tid >> 4, c = tid & 15;
        float acc[4][4] = {};
        for (int d0 = 0; d0 < ND; d0 += 32) {
            __syncthreads();
            #pragma unroll
            for (int i = 0; i < 2; ++i) {
                int sid = tid + i * 256;
                int row = sid >> 3, seg = sid & 7;
                *(float4*)&Wa[row][seg * 4] = *(const float4*)&A [(size_t)(j0 + row) * ND + d0 + seg * 4];
                *(float4*)&Wb[row][seg * 4] = *(const float4*)&Bm[(size_t)(i0 + row) * ND + d0 + seg * 4];
            }
            __syncthreads();
            #pragma unroll 8
            for (int d = 0; d < 32; ++d) {
                float a0 = Wa[r*4+0][d], a1 = Wa[r*4+1][d], a2 = Wa[r*4+2][d], a3 = Wa[r*4+3][d];
                float b0 = Wb[c*4+0][d], b1 = Wb[c*4+1][d], b2 = Wb[c*4+2][d], b3 = Wb[c*4+3][d];
                acc[0][0] += a0*b0; acc[0][1] += a0*b1; acc[0][2] += a0*b2; acc[0][3] += a0*b3;
                acc[1][0] += a1*b0; acc[1][1] += a1*b1; acc[1][2] += a1*b2; acc[1][3] += a1*b3;
                acc[2][0] += a2*b0; acc[2][1] += a2*b1; acc[2][2] += a2*b2; acc[2][3] += a2*b3;
                acc[3][0] += a3*b0; acc[3][1] += a3*b1; acc[3][2] += a3*b2; acc[3][3] += a3*b3;
            }
        }
        #pragma unroll
        for (int a = 0; a < 4; ++a)
            #pragma unroll
            for (int bb = 0; bb < 4; ++bb)
                Mth[(size_t)h * ND * ND + (size_t)(j0 + r * 4 + a) * ND + (i0 + c * 4 + bb)] = (f16)acc[a][bb];
    } else if (bid < 128 + 4096) {
        // ---- convert E -> f16
        const int n4 = NB * NS * ND / 4;
        int i = (bid - 128) * 256 + tid;
        const float* src; f16* dst;
        if (i < n4) { src = Et_in; dst = Ot; }
        else        { src = Ei_in; dst = Oi; i -= n4; }
        float4 v = ((const float4*)src)[i];
        f16x4 o = { (f16)v.x, (f16)v.y, (f16)v.z, (f16)v.w };
        ((f16x4*)dst)[i] = o;
    } else if (bid < 128 + 8192) {
        // ---- Bvec = sum over FB
        int wid = ((bid - 128 - 4096) * 256 + tid) >> 6;
        int lane = tid & 63;
        const float* src; float* dst; int row;
        if (wid < NB * NS) { src = Bt_in; dst = Bt; row = wid; }
        else               { src = Bi_in; dst = Bi; row = wid - NB * NS; }
        float2 v = ((const float2*)(src + (size_t)row * NFB))[lane];
        float s = waveReduceSum(v.x + v.y);
        if (lane == 0) dst[row] = s;
    } else {
        // ---- Cv = 0.5*KLD(Ci,Cm)+0.5*KLD(Ct,Cm)
        int gw = ((bid - 128 - 8192) * 256 + tid) >> 6;
        int lane = tid & 63;
        const float* pt = Ct + ((size_t)gw * NK + lane) * NFC;
        const float* pi = Ci + ((size_t)gw * NK + lane) * NFC;
        float st = 0.f, si = 0.f;
        #pragma unroll
        for (int j = 0; j < NFC; j += 4) {
            float4 vt = *(const float4*)(pt + j); st += vt.x + vt.y + vt.z + vt.w;
            float4 vi = *(const float4*)(pi + j); si += vi.x + vi.y + vi.z + vi.w;
        }
        float cm = 0.5f * (st + si);
        float yp = fminf(fmaxf(cm, 1e-7f), 1.0f);
        float y1 = fminf(fmaxf(si, 1e-7f), 1.0f);
        float y2 = fminf(fmaxf(st, 1e-7f), 1.0f);
        float term = 0.5f * (y1 * logf(y1 / yp) + y2 * logf(y2 / yp));
        term = waveReduceSum(term);
        if (lane == 0) Cv[gw] = term;
    }
}

// ---------------------------------------------------------------- attn4 (R15)
// R13 (best: 303.6us e2e, attn 114.5us, VGPR 124 clean) + ONE change: phase-1 Ms staging now uses
// the SAME 1-barrier/iter double-buffer pattern as the proven phase 2 (reg prefetch of tile jc+1
// -> compute cur -> ds_write next -> barrier), ping-ponging the two 32-row buffers. Cuts 16
// barriers -> 9 and hides the 16KB/iter staging under the 32-MFMA block. Ops identical to R13,
// only cadence changes. Peak arch regs ~144 in phase 1 (mv[4] added) — still <=256, so 2
// waves/SIMD occupancy unchanged; watching for the allocator's 80-reg spill mode (revert signal:
// VGPR<=80 + WRITE_SIZE spike).
__global__ __launch_bounds__(256, 2) void k_attn4(const f16* __restrict__ Eft, const f16* __restrict__ Efi,
                                                  const f16* __restrict__ Mth,
                                                  const float* __restrict__ Bst, const float* __restrict__ Bsi,
                                                  float* __restrict__ PEt, float* __restrict__ PBt,
                                                  float* __restrict__ PEi, float* __restrict__ PBi) {
    int x = blockIdx.x;
    const f16* E; const float* Bvg; float *PE, *PB;
    if (x < 512) { E = Eft; Bvg = Bst; PE = PEt; PB = PBt; }
    else         { x -= 512; E = Efi; Bvg = Bsi; PE = PEi; PB = PBi; }
    int b = x >> 5, h = (x >> 2) & 7;
    int sc = x & 3;
    int s0 = sc * 128;
    const f16* Ebase = E + (size_t)b * NS * ND;
    const f16* Mh = Mth + (size_t)h * ND * ND;
    float* PEo = PE + (size_t)((b * NH + h) * 4 + sc) * NS;
    float* PBo = PB + (size_t)((b * NH + h) * 4 + sc) * NS;

    __shared__ f16 smem[2 * 32 * 264];      // two 32-row buffers, ping-pong in BOTH phases
    __shared__ float pe_s[NS], pb_s[NS];

    int tid = threadIdx.x;
    int lane = tid & 63, w = tid >> 6;
    int l16 = lane & 15, ch = lane >> 4;

    pe_s[tid] = 0.f; pe_s[tid + 256] = 0.f;
    pb_s[tid] = 0.f; pb_s[tid + 256] = 0.f;

    int sw0 = s0 + w * 32;   // this wave's 32 s-rows

    // hoist E B-frags for the P-phase (standard layout): 16 x 16B = 64 VGPRs
    f16x8 ebf[2][8];
    #pragma unroll
    for (int st = 0; st < 2; ++st)
        #pragma unroll
        for (int ki = 0; ki < 8; ++ki)
            ebf[st][ki] = *(const f16x8*)&Ebase[(size_t)(sw0 + st * 16 + l16) * ND + ki * 32 + ch * 8];

    // B-weights for this lane's 8 accumulator s-rows (s = sw0 + st*16 + 4*ch + r)
    float bvr[2][4];
    #pragma unroll
    for (int st = 0; st < 2; ++st)
        #pragma unroll
        for (int r = 0; r < 4; ++r)
            bvr[st][r] = Bvg[b * NS + sw0 + st * 16 + 4 * ch + r];

    // ---- phase 1: P into af[st][jc], double-buffered Ms tiles, 1 barrier/iter
    // prologue: stage tile jc=0 into buf0
    #pragma unroll
    for (int i = 0; i < 4; ++i) {
        int sid = tid + i * 256;
        int row = sid >> 5, seg = sid & 31;    // 32 rows x 32 segs of 16B
        *(int4*)&smem[row * 264 + seg * 8] = *(const int4*)&Mh[(size_t)row * ND + seg * 8];
    }
    f16x8 af[2][8];
    #pragma unroll
    for (int jc = 0; jc < 8; ++jc) {
        f16* cur = smem + (jc & 1) * (32 * 264);
        f16* nxt = smem + ((jc + 1) & 1) * (32 * 264);
        int4 mv[4];
        if (jc < 7) {
            int r0n = (jc + 1) * 32;
            #pragma unroll
            for (int i = 0; i < 4; ++i) {
                int sid = tid + i * 256;
                int row = sid >> 5, seg = sid & 31;
                mv[i] = *(const int4*)&Mh[(size_t)(r0n + row) * ND + seg * 8];
            }
        }
        __syncthreads();   // cur writes visible; nxt reads (iter jc-1) done
        f32x4 acc[2][2] = {};   // [jTile(m)][sTile(n)]
        #pragma unroll
        for (int ki = 0; ki < 8; ++ki) {
            f16x8 a0 = *(const f16x8*)&cur[(l16)      * 264 + ki * 32 + ch * 8];
            f16x8 a1 = *(const f16x8*)&cur[(16 + l16) * 264 + ki * 32 + ch * 8];
            acc[0][0] = mfma16(a0, ebf[0][ki], acc[0][0]);
            acc[0][1] = mfma16(a0, ebf[1][ki], acc[0][1]);
            acc[1][0] = mfma16(a1, ebf[0][ki], acc[1][0]);
            acc[1][1] = mfma16(a1, ebf[1][ki], acc[1][1]);
        }
        if (jc < 7) {
            #pragma unroll
            for (int i = 0; i < 4; ++i) {
                int sid = tid + i * 256;
                int row = sid >> 5, seg = sid & 31;
                *(int4*)&nxt[row * 264 + seg * 8] = mv[i];
            }
        }
        #pragma unroll
        for (int st = 0; st < 2; ++st) {
            f16x8 v;
            #pragma unroll
            for (int r = 0; r < 4; ++r) { v[r] = (f16)acc[0][st][r]; v[4 + r] = (f16)acc[1][st][r]; }
            af[st][jc] = v;
        }
    }
    __syncthreads();   // last Ms reads (buf1) done before phase 2 reuses buffers

    // ---- phase 2: double-buffered t-sweep, 32-row tiles, 1 barrier/iter (proven R13 path)
    int4 v[4];
    #pragma unroll
    for (int i = 0; i < 4; ++i) {
        int sid = tid + i * 256;
        int row = sid >> 5, seg = sid & 31;
        v[i] = *(const int4*)&Ebase[(size_t)row * ND + seg * 8];
    }
    #pragma unroll
    for (int i = 0; i < 4; ++i) {
        int sid = tid + i * 256;
        int row = sid >> 5, seg = sid & 31;
        *(int4*)&smem[row * 264 + seg * 8] = v[i];
    }

    for (int t = 0; t < 16; ++t) {
        f16* cur = smem + (t & 1) * (32 * 264);
        f16* nxt = smem + ((t + 1) & 1) * (32 * 264);
        if (t < 15) {
            int t0n = (t + 1) * 32;
            #pragma unroll
            for (int i = 0; i < 4; ++i) {
                int sid = tid + i * 256;
                int row = sid >> 5, seg = sid & 31;
                v[i] = *(const int4*)&Ebase[(size_t)(t0n + row) * ND + seg * 8];
            }
        }
        __syncthreads();   // cur writes visible; nxt reads (iter t-1) done
        int t0 = t * 32;
        f32x4 sacc[2][2] = {};   // [sTile(m)][tTile(n)]
        #pragma unroll
        for (int kk = 0; kk < 8; ++kk)
            #pragma unroll
            for (int nt = 0; nt < 2; ++nt) {
                const f16* ep = &cur[(nt * 16 + l16) * 264 + kk * 32 + 4 * ch];
                f16x4 lo = *(const f16x4*)ep;
                f16x4 hi = *(const f16x4*)(ep + 16);
                f16x8 bf = { lo[0], lo[1], lo[2], lo[3], hi[0], hi[1], hi[2], hi[3] };
                sacc[0][nt] = mfma16(af[0][kk], bf, sacc[0][nt]);
                sacc[1][nt] = mfma16(af[1][kk], bf, sacc[1][nt]);
            }
        if (t < 15) {
            #pragma unroll
            for (int i = 0; i < 4; ++i) {
                int sid = tid + i * 256;
                int row = sid >> 5, seg = sid & 31;
                *(int4*)&nxt[row * 264 + seg * 8] = v[i];
            }
        }
        #pragma unroll
        for (int nt = 0; nt < 2; ++nt) {
            float se = 0.f, sw = 0.f;
            #pragma unroll
            for (int st = 0; st < 2; ++st)
                #pragma unroll
                for (int r = 0; r < 4; ++r) {
                    float e = __expf(sacc[st][nt][r] * 0.0625f);
                    se += e; sw += bvr[st][r] * e;
                }
            se += __shfl_down(se, 32); se += __shfl_down(se, 16);
            sw += __shfl_down(sw, 32); sw += __shfl_down(sw, 16);
            if (ch == 0) {
                atomicAdd(&pe_s[t0 + nt * 16 + l16], se);
                atomicAdd(&pb_s[t0 + nt * 16 + l16], sw);
            }
        }
    }
    __syncthreads();
    // flush partials: plain coalesced stores to this block's private (b,h,sc) slice — no atomics
    PEo[tid]       = pe_s[tid];
    PEo[tid + 256] = pe_s[tid + 256];
    PBo[tid]       = pb_s[tid];
    PBo[tid + 256] = pb_s[tid + 256];
}

// ---------------------------------------------------------------- cos stage: reduce sc-partials, tv/iv per (b,h,s)
__global__ __launch_bounds__(512) void k_cos(const float* __restrict__ PEt, const float* __restrict__ PBt,
                                             const float* __restrict__ PEi, const float* __restrict__ PBi,
                                             float* __restrict__ TV, float* __restrict__ IV) {
    int bh = blockIdx.x;          // b*NH + h, 0..127
    int s = threadIdx.x;
    float pet = 0.f, pbt = 0.f, pei = 0.f, pbi = 0.f;
    #pragma unroll
    for (int sc = 0; sc < 4; ++sc) {
        size_t idx = (size_t)(bh * 4 + sc) * NS + s;
        pet += PEt[idx]; pbt += PBt[idx];
        pei += PEi[idx]; pbi += PBi[idx];
    }
    TV[(size_t)bh * NS + s] = pbt / pet;
    IV[(size_t)bh * NS + s] = pbi / pei;
}

// ---------------------------------------------------------------- cos + 2x layernorm + combine
__device__ inline float blockSum512(float v, float* rbuf) {
    v = waveReduceSum(v);
    int lane = threadIdx.x & 63, w = threadIdx.x >> 6;
    __syncthreads();
    if (lane == 0) rbuf[w] = v;
    __syncthreads();
    float s = 0.f;
    #pragma unroll
    for (int i = 0; i < 8; ++i) s += rbuf[i];
    return s;
}

__global__ __launch_bounds__(512) void k_final(const float* __restrict__ TV, const float* __restrict__ IV,
                                               const float* __restrict__ Cv,
                                               const float* __restrict__ gbs, const float* __restrict__ bbs,
                                               const float* __restrict__ gcs, const float* __restrict__ bcs,
                                               float* __restrict__ out) {
    __shared__ float rbuf[8];
    int b = blockIdx.x, s = threadIdx.x;
    float dot = 0.f, nt = 0.f, nu = 0.f;
    #pragma unroll
    for (int h = 0; h < NH; ++h) {
        float tv = TV[(size_t)(b * NH + h) * NS + s];
        float iv = IV[(size_t)(b * NH + h) * NS + s];
        dot += tv * iv; nt += tv * tv; nu += iv * iv;
    }
    float cosv = -(dot * rsqrtf(fmaxf(nt, 1e-12f)) * rsqrtf(fmaxf(nu, 1e-12f)));

    float mc = blockSum512(cosv, rbuf) * (1.f / 512.f);
    float dc = cosv - mc;
    float vc = blockSum512(dc * dc, rbuf) * (1.f / 512.f);
    float BS = dc * rsqrtf(vc + 1e-16f) * gbs[s] + bbs[s];

    float cv = Cv[(size_t)b * NS + s];
    float mv = blockSum512(cv, rbuf) * (1.f / 512.f);
    float dv = cv - mv;
    float vv = blockSum512(dv * dv, rbuf) * (1.f / 512.f);
    float CS = dv * rsqrtf(vv + 1e-16f) * gcs[s] + bcs[s];

    out[(size_t)b * NS + s] = BS + CS;
    out[(size_t)NB * NS + (size_t)b * NS + s] = BS;
    out[(size_t)2 * NB * NS + (size_t)b * NS + s] = CS;
}

extern "C" void kernel_launch(void* const* d_in, const int* in_sizes, int n_in,
                              void* d_out, int out_size, void* d_ws, size_t ws_size,
                              hipStream_t stream) {
    const float* B_target   = (const float*)d_in[0];
    const float* B_infected = (const float*)d_in[1];
    const float* E_target   = (const float*)d_in[2];
    const float* E_infected = (const float*)d_in[3];
    const float* C_target   = (const float*)d_in[4];
    const float* C_infected = (const float*)d_in[5];
    const float* W1  = (const float*)d_in[8];
    const float* W2  = (const float*)d_in[9];
    const float* gbs = (const float*)d_in[10];
    const float* bbs = (const float*)d_in[11];
    const float* gcs = (const float*)d_in[12];
    const float* bcs = (const float*)d_in[13];
    float* out = (float*)d_out;

    char* ws = (char*)d_ws;
    size_t off = 0;
    auto alloc = [&](size_t n) { char* p = ws + off; off = (off + n + 255) & ~(size_t)255; return p; };
    float* Bt  = (float*)alloc((size_t)NB * NS * 4);
    float* Bi  = (float*)alloc((size_t)NB * NS * 4);
    float* Cv  = (float*)alloc((size_t)NB * NS * 4);
    float* PEt = (float*)alloc((size_t)NB * NH * 4 * NS * 4);   // per-(b,h,sc) partials
    float* PBt = (float*)alloc((size_t)NB * NH * 4 * NS * 4);
    float* PEi = (float*)alloc((size_t)NB * NH * 4 * NS * 4);
    float* PBi = (float*)alloc((size_t)NB * NH * 4 * NS * 4);
    float* TV  = (float*)alloc((size_t)NB * NH * NS * 4);
    float* IV  = (float*)alloc((size_t)NB * NH * NS * 4);
    f16* Mth = (f16*)alloc((size_t)NH * ND * ND * 2);
    f16* Eft = (f16*)alloc((size_t)NB * NS * ND * 2);
    f16* Efi = (f16*)alloc((size_t)NB * NS * ND * 2);

    k_prep<<<128 + 8192 + 2048, 256, 0, stream>>>(W1, W2, Mth,
                                                  E_target, E_infected, Eft, Efi,
                                                  B_target, B_infected, Bt, Bi,
                                                  C_target, C_infected, Cv);
    k_attn4<<<1024, 256, 0, stream>>>(Eft, Efi, Mth, Bt, Bi, PEt, PBt, PEi, PBi);
    k_cos<<<NB * NH, 512, 0, stream>>>(PEt, PBt, PEi, PBi, TV, IV);
    k_final<<<NB, 512, 0, stream>>>(TV, IV, Cv, gbs, bbs, gcs, bcs, out);
}

// Round 11
// 305.986 us; speedup vs baseline: 1.1410x; 1.0385x over previous
//
#include <hip/hip_runtime.h>

#define NB 16
#define NS 512
#define ND 256
#define NH 8
#define NFB 128
#define NK 64
#define NFC 32

using f16 = _Float16;
using f16x4 = __attribute__((ext_vector_type(4))) f16;
using f16x8 = __attribute__((ext_vector_type(8))) f16;
using f32x4 = __attribute__((ext_vector_type(4))) float;

__device__ inline float waveReduceSum(float v) {
    #pragma unroll
    for (int off = 32; off; off >>= 1) v += __shfl_down(v, off);
    return v;
}

__device__ inline f32x4 mfma16(f16x8 a, f16x8 b, f32x4 c) {
    return __builtin_amdgcn_mfma_f32_16x16x32_f16(a, b, c, 0, 0, 0);
}

// ---------------------------------------------------------------- prep: mt | convert | bsum | cv in one dispatch
// R16: Wa/Wb padded [64][36] -> [64][37]. With stride 36, the inner-loop column reads
// Wb[c*4+b][d] map 16 distinct rows onto banks (row*4+d)%32 = 2 banks -> 8-way conflict
// (~2.9x serialization, m136). Stride 37 gives banks (row*5+d)%32: Wa -> 4 distinct banks
// (conflict-free), Wb -> 2 addrs/bank (2-way = free). Mt section is LDS-read-bound: ~2048
// scalar ds_read_b32/thread, so this is the k_prep lever.
__global__ __launch_bounds__(256) void k_prep(const float* __restrict__ W1, const float* __restrict__ W2,
                                              f16* __restrict__ Mth,
                                              const float* __restrict__ Et_in, const float* __restrict__ Ei_in,
                                              f16* __restrict__ Ot, f16* __restrict__ Oi,
                                              const float* __restrict__ Bt_in, const float* __restrict__ Bi_in,
                                              float* __restrict__ Bt, float* __restrict__ Bi,
                                              const float* __restrict__ Ct, const float* __restrict__ Ci,
                                              float* __restrict__ Cv) {
    __shared__ float Wa[64][37];
    __shared__ float Wb[64][37];
    int bid = blockIdx.x;
    int tid = threadIdx.x;

    if (bid < 128) {
        // ---- Mt[h][j][i] = sum_e W2[h,j,e]*W1[h,i,e]
        int h  = bid >> 4;
        int j0 = ((bid >> 2) & 3) * 64;
        int i0 = (bid & 3) * 64;
        const float* A  = W2 + (size_t)h * ND * ND;
        const float* Bm = W1 + (size_t)h * ND * ND;
        int r = tid >> 4, c = tid & 15;
        float acc[4][4] = {};
        for (int d0 = 0; d0 < ND; d0 += 32) {
            __syncthreads();
            #pragma unroll
            for (int i = 0; i < 2; ++i) {
                int sid = tid + i * 256;
                int row = sid >> 3, seg = sid & 7;
                *(float4*)&Wa[row][seg * 4] = *(const float4*)&A [(size_t)(j0 + row) * ND + d0 + seg * 4];
                *(float4*)&Wb[row][seg * 4] = *(const float4*)&Bm[(size_t)(i0 + row) * ND + d0 + seg * 4];
            }
            __syncthreads();
            #pragma unroll 8
            for (int d = 0; d < 32; ++d) {
                float a0 = Wa[r*4+0][d], a1 = Wa[r*4+1][d], a2 = Wa[r*4+2][d], a3 = Wa[r*4+3][d];
                float b0 = Wb[c*4+0][d], b1 = Wb[c*4+1][d], b2 = Wb[c*4+2][d], b3 = Wb[c*4+3][d];
                acc[0][0] += a0*b0; acc[0][1] += a0*b1; acc[0][2] += a0*b2; acc[0][3] += a0*b3;
                acc[1][0] += a1*b0; acc[1][1] += a1*b1; acc[1][2] += a1*b2; acc[1][3] += a1*b3;
                acc[2][0] += a2*b0; acc[2][1] += a2*b1; acc[2][2] += a2*b2; acc[2][3] += a2*b3;
                acc[3][0] += a3*b0; acc[3][1] += a3*b1; acc[3][2] += a3*b2; acc[3][3] += a3*b3;
            }
        }
        #pragma unroll
        for (int a = 0; a < 4; ++a)
            #pragma unroll
            for (int bb = 0; bb < 4; ++bb)
                Mth[(size_t)h * ND * ND + (size_t)(j0 + r * 4 + a) * ND + (i0 + c * 4 + bb)] = (f16)acc[a][bb];
    } else if (bid < 128 + 4096) {
        // ---- convert E -> f16
        const int n4 = NB * NS * ND / 4;
        int i = (bid - 128) * 256 + tid;
        const float* src; f16* dst;
        if (i < n4) { src = Et_in; dst = Ot; }
        else        { src = Ei_in; dst = Oi; i -= n4; }
        float4 v = ((const float4*)src)[i];
        f16x4 o = { (f16)v.x, (f16)v.y, (f16)v.z, (f16)v.w };
        ((f16x4*)dst)[i] = o;
    } else if (bid < 128 + 8192) {
        // ---- Bvec = sum over FB
        int wid = ((bid - 128 - 4096) * 256 + tid) >> 6;
        int lane = tid & 63;
        const float* src; float* dst; int row;
        if (wid < NB * NS) { src = Bt_in; dst = Bt; row = wid; }
        else               { src = Bi_in; dst = Bi; row = wid - NB * NS; }
        float2 v = ((const float2*)(src + (size_t)row * NFB))[lane];
        float s = waveReduceSum(v.x + v.y);
        if (lane == 0) dst[row] = s;
    } else {
        // ---- Cv = 0.5*KLD(Ci,Cm)+0.5*KLD(Ct,Cm)
        int gw = ((bid - 128 - 8192) * 256 + tid) >> 6;
        int lane = tid & 63;
        const float* pt = Ct + ((size_t)gw * NK + lane) * NFC;
        const float* pi = Ci + ((size_t)gw * NK + lane) * NFC;
        float st = 0.f, si = 0.f;
        #pragma unroll
        for (int j = 0; j < NFC; j += 4) {
            float4 vt = *(const float4*)(pt + j); st += vt.x + vt.y + vt.z + vt.w;
            float4 vi = *(const float4*)(pi + j); si += vi.x + vi.y + vi.z + vi.w;
        }
        float cm = 0.5f * (st + si);
        float yp = fminf(fmaxf(cm, 1e-7f), 1.0f);
        float y1 = fminf(fmaxf(si, 1e-7f), 1.0f);
        float y2 = fminf(fmaxf(st, 1e-7f), 1.0f);
        float term = 0.5f * (y1 * logf(y1 / yp) + y2 * logf(y2 / yp));
        term = waveReduceSum(term);
        if (lane == 0) Cv[gw] = term;
    }
}

// ---------------------------------------------------------------- attn4 (R16 = R13 exact, the proven best:
// 303.6us e2e, attn 114.5us, VGPR 124 clean). P in VGPRs, 2-barrier/jc phase-1 staging, 32-row
// double-buffered phase-2 t-sweep, private-slice flush. R15 proved the 1-barrier phase-1 pipeline
// regresses (129.5us) despite fewer barriers — compiler schedules the naive form better. Frozen.
__global__ __launch_bounds__(256, 2) void k_attn4(const f16* __restrict__ Eft, const f16* __restrict__ Efi,
                                                  const f16* __restrict__ Mth,
                                                  const float* __restrict__ Bst, const float* __restrict__ Bsi,
                                                  float* __restrict__ PEt, float* __restrict__ PBt,
                                                  float* __restrict__ PEi, float* __restrict__ PBi) {
    int x = blockIdx.x;
    const f16* E; const float* Bvg; float *PE, *PB;
    if (x < 512) { E = Eft; Bvg = Bst; PE = PEt; PB = PBt; }
    else         { x -= 512; E = Efi; Bvg = Bsi; PE = PEi; PB = PBi; }
    int b = x >> 5, h = (x >> 2) & 7;
    int sc = x & 3;
    int s0 = sc * 128;
    const f16* Ebase = E + (size_t)b * NS * ND;
    const f16* Mh = Mth + (size_t)h * ND * ND;
    float* PEo = PE + (size_t)((b * NH + h) * 4 + sc) * NS;
    float* PBo = PB + (size_t)((b * NH + h) * 4 + sc) * NS;

    __shared__ f16 smem[2 * 32 * 264];      // two 32-row buffers; phase1 Ms uses buffer 0 only
    __shared__ float pe_s[NS], pb_s[NS];

    int tid = threadIdx.x;
    int lane = tid & 63, w = tid >> 6;
    int l16 = lane & 15, ch = lane >> 4;

    pe_s[tid] = 0.f; pe_s[tid + 256] = 0.f;
    pb_s[tid] = 0.f; pb_s[tid + 256] = 0.f;

    int sw0 = s0 + w * 32;   // this wave's 32 s-rows

    // hoist E B-frags for the P-phase (standard layout): 16 x 16B = 64 VGPRs
    f16x8 ebf[2][8];
    #pragma unroll
    for (int st = 0; st < 2; ++st)
        #pragma unroll
        for (int ki = 0; ki < 8; ++ki)
            ebf[st][ki] = *(const f16x8*)&Ebase[(size_t)(sw0 + st * 16 + l16) * ND + ki * 32 + ch * 8];

    // B-weights for this lane's 8 accumulator s-rows (s = sw0 + st*16 + 4*ch + r)
    float bvr[2][4];
    #pragma unroll
    for (int st = 0; st < 2; ++st)
        #pragma unroll
        for (int r = 0; r < 4; ++r)
            bvr[st][r] = Bvg[b * NS + sw0 + st * 16 + 4 * ch + r];

    // ---- phase 1: P into af[st][jc] (A-frag form, permuted k-map slot(ch,j') -> 16*(j'>>2)+4*ch+(j'&3))
    f16x8 af[2][8];
    #pragma unroll
    for (int jc = 0; jc < 8; ++jc) {
        __syncthreads();
        #pragma unroll
        for (int it = 0; it < 4; ++it) {
            int sid = tid + it * 256;
            int row = sid >> 5, seg = sid & 31;    // 32 rows x 32 segs of 16B
            *(int4*)&smem[row * 264 + seg * 8] = *(const int4*)&Mh[(size_t)(jc * 32 + row) * ND + seg * 8];
        }
        __syncthreads();
        f32x4 acc[2][2] = {};   // [jTile(m)][sTile(n)]
        #pragma unroll
        for (int ki = 0; ki < 8; ++ki) {
            f16x8 a0 = *(const f16x8*)&smem[(l16)      * 264 + ki * 32 + ch * 8];
            f16x8 a1 = *(const f16x8*)&smem[(16 + l16) * 264 + ki * 32 + ch * 8];
            acc[0][0] = mfma16(a0, ebf[0][ki], acc[0][0]);
            acc[0][1] = mfma16(a0, ebf[1][ki], acc[0][1]);
            acc[1][0] = mfma16(a1, ebf[0][ki], acc[1][0]);
            acc[1][1] = mfma16(a1, ebf[1][ki], acc[1][1]);
        }
        #pragma unroll
        for (int st = 0; st < 2; ++st) {
            f16x8 v;
            #pragma unroll
            for (int r = 0; r < 4; ++r) { v[r] = (f16)acc[0][st][r]; v[4 + r] = (f16)acc[1][st][r]; }
            af[st][jc] = v;
        }
    }
    __syncthreads();   // last Ms reads done before buffer 0 is overwritten

    // ---- phase 2: double-buffered t-sweep, 32-row tiles, 1 barrier/iter
    int4 v[4];
    #pragma unroll
    for (int i = 0; i < 4; ++i) {
        int sid = tid + i * 256;
        int row = sid >> 5, seg = sid & 31;
        v[i] = *(const int4*)&Ebase[(size_t)row * ND + seg * 8];
    }
    #pragma unroll
    for (int i = 0; i < 4; ++i) {
        int sid = tid + i * 256;
        int row = sid >> 5, seg = sid & 31;
        *(int4*)&smem[row * 264 + seg * 8] = v[i];
    }

    for (int t = 0; t < 16; ++t) {
        f16* cur = smem + (t & 1) * (32 * 264);
        f16* nxt = smem + ((t + 1) & 1) * (32 * 264);
        if (t < 15) {
            int t0n = (t + 1) * 32;
            #pragma unroll
            for (int i = 0; i < 4; ++i) {
                int sid = tid + i * 256;
                int row = sid >> 5, seg = sid & 31;
                v[i] = *(const int4*)&Ebase[(size_t)(t0n + row) * ND + seg * 8];
            }
        }
        __syncthreads();   // cur writes visible; nxt reads (iter t-1) done
        int t0 = t * 32;
        f32x4 sacc[2][2] = {};   // [sTile(m)][tTile(n)]
        #pragma unroll
        for (int kk = 0; kk < 8; ++kk)
            #pragma unroll
            for (int nt = 0; nt < 2; ++nt) {
                const f16* ep = &cur[(nt * 16 + l16) * 264 + kk * 32 + 4 * ch];
                f16x4 lo = *(const f16x4*)ep;
                f16x4 hi = *(const f16x4*)(ep + 16);
                f16x8 bf = { lo[0], lo[1], lo[2], lo[3], hi[0], hi[1], hi[2], hi[3] };
                sacc[0][nt] = mfma16(af[0][kk], bf, sacc[0][nt]);
                sacc[1][nt] = mfma16(af[1][kk], bf, sacc[1][nt]);
            }
        if (t < 15) {
            #pragma unroll
            for (int i = 0; i < 4; ++i) {
                int sid = tid + i * 256;
                int row = sid >> 5, seg = sid & 31;
                *(int4*)&nxt[row * 264 + seg * 8] = v[i];
            }
        }
        #pragma unroll
        for (int nt = 0; nt < 2; ++nt) {
            float se = 0.f, sw = 0.f;
            #pragma unroll
            for (int st = 0; st < 2; ++st)
                #pragma unroll
                for (int r = 0; r < 4; ++r) {
                    float e = __expf(sacc[st][nt][r] * 0.0625f);
                    se += e; sw += bvr[st][r] * e;
                }
            se += __shfl_down(se, 32); se += __shfl_down(se, 16);
            sw += __shfl_down(sw, 32); sw += __shfl_down(sw, 16);
            if (ch == 0) {
                atomicAdd(&pe_s[t0 + nt * 16 + l16], se);
                atomicAdd(&pb_s[t0 + nt * 16 + l16], sw);
            }
        }
    }
    __syncthreads();
    // flush partials: plain coalesced stores to this block's private (b,h,sc) slice — no atomics
    PEo[tid]       = pe_s[tid];
    PEo[tid + 256] = pe_s[tid + 256];
    PBo[tid]       = pb_s[tid];
    PBo[tid + 256] = pb_s[tid + 256];
}

// ---------------------------------------------------------------- fused: sc-reduce + cos + 2x layernorm + combine
// R16: k_cos folded in — drops one dispatch and the 16.8 MB TV/IV round-trip.
__device__ inline float waveReduceSumF(float v) {
    #pragma unroll
    for (int off = 32; off; off >>= 1) v += __shfl_down(v, off);
    return v;
}

__device__ inline float blockSum512(float v, float* rbuf) {
    v = waveReduceSumF(v);
    int lane = threadIdx.x & 63, w = threadIdx.x >> 6;
    __syncthreads();
    if (lane == 0) rbuf[w] = v;
    __syncthreads();
    float s = 0.f;
    #pragma unroll
    for (int i = 0; i < 8; ++i) s += rbuf[i];
    return s;
}

__global__ __launch_bounds__(512) void k_final(const float* __restrict__ PEt, const float* __restrict__ PBt,
                                               const float* __restrict__ PEi, const float* __restrict__ PBi,
                                               const float* __restrict__ Cv,
                                               const float* __restrict__ gbs, const float* __restrict__ bbs,
                                               const float* __restrict__ gcs, const float* __restrict__ bcs,
                                               float* __restrict__ out) {
    __shared__ float rbuf[8];
    int b = blockIdx.x, s = threadIdx.x;
    float dot = 0.f, nt = 0.f, nu = 0.f;
    #pragma unroll
    for (int h = 0; h < NH; ++h) {
        float pet = 0.f, pbt = 0.f, pei = 0.f, pbi = 0.f;
        #pragma unroll
        for (int sc = 0; sc < 4; ++sc) {
            size_t idx = (size_t)((b * NH + h) * 4 + sc) * NS + s;
            pet += PEt[idx]; pbt += PBt[idx];
            pei += PEi[idx]; pbi += PBi[idx];
        }
        float tv = pbt / pet;
        float iv = pbi / pei;
        dot += tv * iv; nt += tv * tv; nu += iv * iv;
    }
    float cosv = -(dot * rsqrtf(fmaxf(nt, 1e-12f)) * rsqrtf(fmaxf(nu, 1e-12f)));

    float mc = blockSum512(cosv, rbuf) * (1.f / 512.f);
    float dc = cosv - mc;
    float vc = blockSum512(dc * dc, rbuf) * (1.f / 512.f);
    float BS = dc * rsqrtf(vc + 1e-16f) * gbs[s] + bbs[s];

    float cv = Cv[(size_t)b * NS + s];
    float mv = blockSum512(cv, rbuf) * (1.f / 512.f);
    float dv = cv - mv;
    float vv = blockSum512(dv * dv, rbuf) * (1.f / 512.f);
    float CS = dv * rsqrtf(vv + 1e-16f) * gcs[s] + bcs[s];

    out[(size_t)b * NS + s] = BS + CS;
    out[(size_t)NB * NS + (size_t)b * NS + s] = BS;
    out[(size_t)2 * NB * NS + (size_t)b * NS + s] = CS;
}

extern "C" void kernel_launch(void* const* d_in, const int* in_sizes, int n_in,
                              void* d_out, int out_size, void* d_ws, size_t ws_size,
                              hipStream_t stream) {
    const float* B_target   = (const float*)d_in[0];
    const float* B_infected = (const float*)d_in[1];
    const float* E_target   = (const float*)d_in[2];
    const float* E_infected = (const float*)d_in[3];
    const float* C_target   = (const float*)d_in[4];
    const float* C_infected = (const float*)d_in[5];
    const float* W1  = (const float*)d_in[8];
    const float* W2  = (const float*)d_in[9];
    const float* gbs = (const float*)d_in[10];
    const float* bbs = (const float*)d_in[11];
    const float* gcs = (const float*)d_in[12];
    const float* bcs = (const float*)d_in[13];
    float* out = (float*)d_out;

    char* ws = (char*)d_ws;
    size_t off = 0;
    auto alloc = [&](size_t n) { char* p = ws + off; off = (off + n + 255) & ~(size_t)255; return p; };
    float* Bt  = (float*)alloc((size_t)NB * NS * 4);
    float* Bi  = (float*)alloc((size_t)NB * NS * 4);
    float* Cv  = (float*)alloc((size_t)NB * NS * 4);
    float* PEt = (float*)alloc((size_t)NB * NH * 4 * NS * 4);   // per-(b,h,sc) partials
    float* PBt = (float*)alloc((size_t)NB * NH * 4 * NS * 4);
    float* PEi = (float*)alloc((size_t)NB * NH * 4 * NS * 4);
    float* PBi = (float*)alloc((size_t)NB * NH * 4 * NS * 4);
    f16* Mth = (f16*)alloc((size_t)NH * ND * ND * 2);
    f16* Eft = (f16*)alloc((size_t)NB * NS * ND * 2);
    f16* Efi = (f16*)alloc((size_t)NB * NS * ND * 2);

    k_prep<<<128 + 8192 + 2048, 256, 0, stream>>>(W1, W2, Mth,
                                                  E_target, E_infected, Eft, Efi,
                                                  B_target, B_infected, Bt, Bi,
                                                  C_target, C_infected, Cv);
    k_attn4<<<1024, 256, 0, stream>>>(Eft, Efi, Mth, Bt, Bi, PEt, PBt, PEi, PBi);
    k_final<<<NB, 512, 0, stream>>>(PEt, PBt, PEi, PBi, Cv, gbs, bbs, gcs, bcs, out);
}

// Round 12
// 303.968 us; speedup vs baseline: 1.1485x; 1.0066x over previous
//
#include <hip/hip_runtime.h>

#define NB 16
#define NS 512
#define ND 256
#define NH 8
#define NFB 128
#define NK 64
#define NFC 32

using f16 = _Float16;
using f16x4 = __attribute__((ext_vector_type(4))) f16;
using f16x8 = __attribute__((ext_vector_type(8))) f16;
using f32x4 = __attribute__((ext_vector_type(4))) float;

__device__ inline float waveReduceSum(float v) {
    #pragma unroll
    for (int off = 32; off; off >>= 1) v += __shfl_down(v, off);
    return v;
}

__device__ inline f32x4 mfma16(f16x8 a, f16x8 b, f32x4 c) {
    return __builtin_amdgcn_mfma_f32_16x16x32_f16(a, b, c, 0, 0, 0);
}

// ---------------------------------------------------------------- prep: mt | convert | bsum | cv in one dispatch
// R17: Mt section rebuilt on MFMA. Old form: 2048 scalar ds_read_b32 + 2048 scalar FMAs per thread
// at 1 wave/SIMD (128 blocks = the k_prep tail, latency-exposed; R16's pad-null proved it wasn't
// conflicts). New: per k-step stage 64x32 W2/W1 tiles as f16 (fp32->f16 inline, per-block so no
// cross-block race), then per wave 1 A-frag + 4 B-frags (16B LDS reads) + 4 MFMA — the operand
// patterns validated in attn4 phase 1. f16-input rounding adds ~6e-5 abs error ~= Mth's own f16
// output rounding (|Mt| ~ 0.06) — safe at absmax tolerance.
__global__ __launch_bounds__(256) void k_prep(const float* __restrict__ W1, const float* __restrict__ W2,
                                              f16* __restrict__ Mth,
                                              const float* __restrict__ Et_in, const float* __restrict__ Ei_in,
                                              f16* __restrict__ Ot, f16* __restrict__ Oi,
                                              const float* __restrict__ Bt_in, const float* __restrict__ Bi_in,
                                              float* __restrict__ Bt, float* __restrict__ Bi,
                                              const float* __restrict__ Ct, const float* __restrict__ Ci,
                                              float* __restrict__ Cv) {
    __shared__ f16 Wfa[64][34];   // stride 34 f16 = 17 words: odd stride spreads banks
    __shared__ f16 Wfb[64][34];
    int bid = blockIdx.x;
    int tid = threadIdx.x;

    if (bid < 128) {
        // ---- Mt[h][j][i] = sum_e W2[h,j,e]*W1[h,i,e]  — MFMA form
        int h  = bid >> 4;
        int j0 = ((bid >> 2) & 3) * 64;
        int i0 = (bid & 3) * 64;
        const float* A  = W2 + (size_t)h * ND * ND;   // rows j
        const float* Bm = W1 + (size_t)h * ND * ND;   // rows i
        int lane = tid & 63, w = tid >> 6;
        int l16 = lane & 15, ch = lane >> 4;

        f32x4 acc[4] = {};
        for (int k0 = 0; k0 < ND; k0 += 32) {
            __syncthreads();
            {
                int row = tid >> 2, seg = tid & 3;    // 64 rows x 4 segs of 8 floats
                const float* pa = &A [(size_t)(j0 + row) * ND + k0 + seg * 8];
                const float* pb = &Bm[(size_t)(i0 + row) * ND + k0 + seg * 8];
                float4 a0 = *(const float4*)pa, a1 = *(const float4*)(pa + 4);
                float4 b0 = *(const float4*)pb, b1 = *(const float4*)(pb + 4);
                f16x8 av = { (f16)a0.x, (f16)a0.y, (f16)a0.z, (f16)a0.w,
                             (f16)a1.x, (f16)a1.y, (f16)a1.z, (f16)a1.w };
                f16x8 bv = { (f16)b0.x, (f16)b0.y, (f16)b0.z, (f16)b0.w,
                             (f16)b1.x, (f16)b1.y, (f16)b1.z, (f16)b1.w };
                *(f16x8*)&Wfa[row][seg * 8] = av;
                *(f16x8*)&Wfb[row][seg * 8] = bv;
            }
            __syncthreads();
            f16x8 afr = *(const f16x8*)&Wfa[w * 16 + l16][ch * 8];
            #pragma unroll
            for (int fi = 0; fi < 4; ++fi) {
                f16x8 bfr = *(const f16x8*)&Wfb[fi * 16 + l16][ch * 8];
                acc[fi] = mfma16(afr, bfr, acc[fi]);
            }
        }
        // D: row = 4*ch + r (within this wave's 16-row j block), col = l16
        #pragma unroll
        for (int fi = 0; fi < 4; ++fi)
            #pragma unroll
            for (int r = 0; r < 4; ++r)
                Mth[(size_t)h * ND * ND + (size_t)(j0 + w * 16 + 4 * ch + r) * ND + (i0 + fi * 16 + l16)] = (f16)acc[fi][r];
    } else if (bid < 128 + 4096) {
        // ---- convert E -> f16
        const int n4 = NB * NS * ND / 4;
        int i = (bid - 128) * 256 + tid;
        const float* src; f16* dst;
        if (i < n4) { src = Et_in; dst = Ot; }
        else        { src = Ei_in; dst = Oi; i -= n4; }
        float4 v = ((const float4*)src)[i];
        f16x4 o = { (f16)v.x, (f16)v.y, (f16)v.z, (f16)v.w };
        ((f16x4*)dst)[i] = o;
    } else if (bid < 128 + 8192) {
        // ---- Bvec = sum over FB
        int wid = ((bid - 128 - 4096) * 256 + tid) >> 6;
        int lane = tid & 63;
        const float* src; float* dst; int row;
        if (wid < NB * NS) { src = Bt_in; dst = Bt; row = wid; }
        else               { src = Bi_in; dst = Bi; row = wid - NB * NS; }
        float2 v = ((const float2*)(src + (size_t)row * NFB))[lane];
        float s = waveReduceSum(v.x + v.y);
        if (lane == 0) dst[row] = s;
    } else {
        // ---- Cv = 0.5*KLD(Ci,Cm)+0.5*KLD(Ct,Cm)
        int gw = ((bid - 128 - 8192) * 256 + tid) >> 6;
        int lane = tid & 63;
        const float* pt = Ct + ((size_t)gw * NK + lane) * NFC;
        const float* pi = Ci + ((size_t)gw * NK + lane) * NFC;
        float st = 0.f, si = 0.f;
        #pragma unroll
        for (int j = 0; j < NFC; j += 4) {
            float4 vt = *(const float4*)(pt + j); st += vt.x + vt.y + vt.z + vt.w;
            float4 vi = *(const float4*)(pi + j); si += vi.x + vi.y + vi.z + vi.w;
        }
        float cm = 0.5f * (st + si);
        float yp = fminf(fmaxf(cm, 1e-7f), 1.0f);
        float y1 = fminf(fmaxf(si, 1e-7f), 1.0f);
        float y2 = fminf(fmaxf(st, 1e-7f), 1.0f);
        float term = 0.5f * (y1 * logf(y1 / yp) + y2 * logf(y2 / yp));
        term = waveReduceSum(term);
        if (lane == 0) Cv[gw] = term;
    }
}

// ---------------------------------------------------------------- attn4 (frozen R13 best: attn 112-114us,
// VGPR 124 clean). P in VGPRs, 2-barrier/jc phase-1 staging, 32-row double-buffered phase-2
// t-sweep, private-slice flush. R15 proved fancier pipelining regresses. Do not touch.
__global__ __launch_bounds__(256, 2) void k_attn4(const f16* __restrict__ Eft, const f16* __restrict__ Efi,
                                                  const f16* __restrict__ Mth,
                                                  const float* __restrict__ Bst, const float* __restrict__ Bsi,
                                                  float* __restrict__ PEt, float* __restrict__ PBt,
                                                  float* __restrict__ PEi, float* __restrict__ PBi) {
    int x = blockIdx.x;
    const f16* E; const float* Bvg; float *PE, *PB;
    if (x < 512) { E = Eft; Bvg = Bst; PE = PEt; PB = PBt; }
    else         { x -= 512; E = Efi; Bvg = Bsi; PE = PEi; PB = PBi; }
    int b = x >> 5, h = (x >> 2) & 7;
    int sc = x & 3;
    int s0 = sc * 128;
    const f16* Ebase = E + (size_t)b * NS * ND;
    const f16* Mh = Mth + (size_t)h * ND * ND;
    float* PEo = PE + (size_t)((b * NH + h) * 4 + sc) * NS;
    float* PBo = PB + (size_t)((b * NH + h) * 4 + sc) * NS;

    __shared__ f16 smem[2 * 32 * 264];      // two 32-row buffers; phase1 Ms uses buffer 0 only
    __shared__ float pe_s[NS], pb_s[NS];

    int tid = threadIdx.x;
    int lane = tid & 63, w = tid >> 6;
    int l16 = lane & 15, ch = lane >> 4;

    pe_s[tid] = 0.f; pe_s[tid + 256] = 0.f;
    pb_s[tid] = 0.f; pb_s[tid + 256] = 0.f;

    int sw0 = s0 + w * 32;   // this wave's 32 s-rows

    // hoist E B-frags for the P-phase (standard layout): 16 x 16B = 64 VGPRs
    f16x8 ebf[2][8];
    #pragma unroll
    for (int st = 0; st < 2; ++st)
        #pragma unroll
        for (int ki = 0; ki < 8; ++ki)
            ebf[st][ki] = *(const f16x8*)&Ebase[(size_t)(sw0 + st * 16 + l16) * ND + ki * 32 + ch * 8];

    // B-weights for this lane's 8 accumulator s-rows (s = sw0 + st*16 + 4*ch + r)
    float bvr[2][4];
    #pragma unroll
    for (int st = 0; st < 2; ++st)
        #pragma unroll
        for (int r = 0; r < 4; ++r)
            bvr[st][r] = Bvg[b * NS + sw0 + st * 16 + 4 * ch + r];

    // ---- phase 1: P into af[st][jc] (A-frag form, permuted k-map slot(ch,j') -> 16*(j'>>2)+4*ch+(j'&3))
    f16x8 af[2][8];
    #pragma unroll
    for (int jc = 0; jc < 8; ++jc) {
        __syncthreads();
        #pragma unroll
        for (int it = 0; it < 4; ++it) {
            int sid = tid + it * 256;
            int row = sid >> 5, seg = sid & 31;    // 32 rows x 32 segs of 16B
            *(int4*)&smem[row * 264 + seg * 8] = *(const int4*)&Mh[(size_t)(jc * 32 + row) * ND + seg * 8];
        }
        __syncthreads();
        f32x4 acc[2][2] = {};   // [jTile(m)][sTile(n)]
        #pragma unroll
        for (int ki = 0; ki < 8; ++ki) {
            f16x8 a0 = *(const f16x8*)&smem[(l16)      * 264 + ki * 32 + ch * 8];
            f16x8 a1 = *(const f16x8*)&smem[(16 + l16) * 264 + ki * 32 + ch * 8];
            acc[0][0] = mfma16(a0, ebf[0][ki], acc[0][0]);
            acc[0][1] = mfma16(a0, ebf[1][ki], acc[0][1]);
            acc[1][0] = mfma16(a1, ebf[0][ki], acc[1][0]);
            acc[1][1] = mfma16(a1, ebf[1][ki], acc[1][1]);
        }
        #pragma unroll
        for (int st = 0; st < 2; ++st) {
            f16x8 v;
            #pragma unroll
            for (int r = 0; r < 4; ++r) { v[r] = (f16)acc[0][st][r]; v[4 + r] = (f16)acc[1][st][r]; }
            af[st][jc] = v;
        }
    }
    __syncthreads();   // last Ms reads done before buffer 0 is overwritten

    // ---- phase 2: double-buffered t-sweep, 32-row tiles, 1 barrier/iter
    int4 v[4];
    #pragma unroll
    for (int i = 0; i < 4; ++i) {
        int sid = tid + i * 256;
        int row = sid >> 5, seg = sid & 31;
        v[i] = *(const int4*)&Ebase[(size_t)row * ND + seg * 8];
    }
    #pragma unroll
    for (int i = 0; i < 4; ++i) {
        int sid = tid + i * 256;
        int row = sid >> 5, seg = sid & 31;
        *(int4*)&smem[row * 264 + seg * 8] = v[i];
    }

    for (int t = 0; t < 16; ++t) {
        f16* cur = smem + (t & 1) * (32 * 264);
        f16* nxt = smem + ((t + 1) & 1) * (32 * 264);
        if (t < 15) {
            int t0n = (t + 1) * 32;
            #pragma unroll
            for (int i = 0; i < 4; ++i) {
                int sid = tid + i * 256;
                int row = sid >> 5, seg = sid & 31;
                v[i] = *(const int4*)&Ebase[(size_t)(t0n + row) * ND + seg * 8];
            }
        }
        __syncthreads();   // cur writes visible; nxt reads (iter t-1) done
        int t0 = t * 32;
        f32x4 sacc[2][2] = {};   // [sTile(m)][tTile(n)]
        #pragma unroll
        for (int kk = 0; kk < 8; ++kk)
            #pragma unroll
            for (int nt = 0; nt < 2; ++nt) {
                const f16* ep = &cur[(nt * 16 + l16) * 264 + kk * 32 + 4 * ch];
                f16x4 lo = *(const f16x4*)ep;
                f16x4 hi = *(const f16x4*)(ep + 16);
                f16x8 bf = { lo[0], lo[1], lo[2], lo[3], hi[0], hi[1], hi[2], hi[3] };
                sacc[0][nt] = mfma16(af[0][kk], bf, sacc[0][nt]);
                sacc[1][nt] = mfma16(af[1][kk], bf, sacc[1][nt]);
            }
        if (t < 15) {
            #pragma unroll
            for (int i = 0; i < 4; ++i) {
                int sid = tid + i * 256;
                int row = sid >> 5, seg = sid & 31;
                *(int4*)&nxt[row * 264 + seg * 8] = v[i];
            }
        }
        #pragma unroll
        for (int nt = 0; nt < 2; ++nt) {
            float se = 0.f, sw = 0.f;
            #pragma unroll
            for (int st = 0; st < 2; ++st)
                #pragma unroll
                for (int r = 0; r < 4; ++r) {
                    float e = __expf(sacc[st][nt][r] * 0.0625f);
                    se += e; sw += bvr[st][r] * e;
                }
            se += __shfl_down(se, 32); se += __shfl_down(se, 16);
            sw += __shfl_down(sw, 32); sw += __shfl_down(sw, 16);
            if (ch == 0) {
                atomicAdd(&pe_s[t0 + nt * 16 + l16], se);
                atomicAdd(&pb_s[t0 + nt * 16 + l16], sw);
            }
        }
    }
    __syncthreads();
    // flush partials: plain coalesced stores to this block's private (b,h,sc) slice — no atomics
    PEo[tid]       = pe_s[tid];
    PEo[tid + 256] = pe_s[tid + 256];
    PBo[tid]       = pb_s[tid];
    PBo[tid + 256] = pb_s[tid + 256];
}

// ---------------------------------------------------------------- fused: sc-reduce + cos + 2x layernorm + combine
__device__ inline float blockSum512(float v, float* rbuf) {
    v = waveReduceSum(v);
    int lane = threadIdx.x & 63, w = threadIdx.x >> 6;
    __syncthreads();
    if (lane == 0) rbuf[w] = v;
    __syncthreads();
    float s = 0.f;
    #pragma unroll
    for (int i = 0; i < 8; ++i) s += rbuf[i];
    return s;
}

__global__ __launch_bounds__(512) void k_final(const float* __restrict__ PEt, const float* __restrict__ PBt,
                                               const float* __restrict__ PEi, const float* __restrict__ PBi,
                                               const float* __restrict__ Cv,
                                               const float* __restrict__ gbs, const float* __restrict__ bbs,
                                               const float* __restrict__ gcs, const float* __restrict__ bcs,
                                               float* __restrict__ out) {
    __shared__ float rbuf[8];
    int b = blockIdx.x, s = threadIdx.x;
    float dot = 0.f, nt = 0.f, nu = 0.f;
    #pragma unroll
    for (int h = 0; h < NH; ++h) {
        float pet = 0.f, pbt = 0.f, pei = 0.f, pbi = 0.f;
        #pragma unroll
        for (int sc = 0; sc < 4; ++sc) {
            size_t idx = (size_t)((b * NH + h) * 4 + sc) * NS + s;
            pet += PEt[idx]; pbt += PBt[idx];
            pei += PEi[idx]; pbi += PBi[idx];
        }
        float tv = pbt / pet;
        float iv = pbi / pei;
        dot += tv * iv; nt += tv * tv; nu += iv * iv;
    }
    float cosv = -(dot * rsqrtf(fmaxf(nt, 1e-12f)) * rsqrtf(fmaxf(nu, 1e-12f)));

    float mc = blockSum512(cosv, rbuf) * (1.f / 512.f);
    float dc = cosv - mc;
    float vc = blockSum512(dc * dc, rbuf) * (1.f / 512.f);
    float BS = dc * rsqrtf(vc + 1e-16f) * gbs[s] + bbs[s];

    float cv = Cv[(size_t)b * NS + s];
    float mv = blockSum512(cv, rbuf) * (1.f / 512.f);
    float dv = cv - mv;
    float vv = blockSum512(dv * dv, rbuf) * (1.f / 512.f);
    float CS = dv * rsqrtf(vv + 1e-16f) * gcs[s] + bcs[s];

    out[(size_t)b * NS + s] = BS + CS;
    out[(size_t)NB * NS + (size_t)b * NS + s] = BS;
    out[(size_t)2 * NB * NS + (size_t)b * NS + s] = CS;
}

extern "C" void kernel_launch(void* const* d_in, const int* in_sizes, int n_in,
                              void* d_out, int out_size, void* d_ws, size_t ws_size,
                              hipStream_t stream) {
    const float* B_target   = (const float*)d_in[0];
    const float* B_infected = (const float*)d_in[1];
    const float* E_target   = (const float*)d_in[2];
    const float* E_infected = (const float*)d_in[3];
    const float* C_target   = (const float*)d_in[4];
    const float* C_infected = (const float*)d_in[5];
    const float* W1  = (const float*)d_in[8];
    const float* W2  = (const float*)d_in[9];
    const float* gbs = (const float*)d_in[10];
    const float* bbs = (const float*)d_in[11];
    const float* gcs = (const float*)d_in[12];
    const float* bcs = (const float*)d_in[13];
    float* out = (float*)d_out;

    char* ws = (char*)d_ws;
    size_t off = 0;
    auto alloc = [&](size_t n) { char* p = ws + off; off = (off + n + 255) & ~(size_t)255; return p; };
    float* Bt  = (float*)alloc((size_t)NB * NS * 4);
    float* Bi  = (float*)alloc((size_t)NB * NS * 4);
    float* Cv  = (float*)alloc((size_t)NB * NS * 4);
    float* PEt = (float*)alloc((size_t)NB * NH * 4 * NS * 4);   // per-(b,h,sc) partials
    float* PBt = (float*)alloc((size_t)NB * NH * 4 * NS * 4);
    float* PEi = (float*)alloc((size_t)NB * NH * 4 * NS * 4);
    float* PBi = (float*)alloc((size_t)NB * NH * 4 * NS * 4);
    f16* Mth = (f16*)alloc((size_t)NH * ND * ND * 2);
    f16* Eft = (f16*)alloc((size_t)NB * NS * ND * 2);
    f16* Efi = (f16*)alloc((size_t)NB * NS * ND * 2);

    k_prep<<<128 + 8192 + 2048, 256, 0, stream>>>(W1, W2, Mth,
                                                  E_target, E_infected, Eft, Efi,
                                                  B_target, B_infected, Bt, Bi,
                                                  C_target, C_infected, Cv);
    k_attn4<<<1024, 256, 0, stream>>>(Eft, Efi, Mth, Bt, Bi, PEt, PBt, PEi, PBi);
    k_final<<<NB, 512, 0, stream>>>(PEt, PBt, PEi, PBi, Cv, gbs, bbs, gcs, bcs, out);
}